// Round 1
// 2093.737 us; speedup vs baseline: 1.6861x; 1.6861x over previous
//
#include <hip/hip_runtime.h>

#define SEQL 4096
#define NB   256
#define NH   64
#define TR   16    // xproj: rows per LDS tile
#define RPB  256   // xproj: rows per block

// ---------------------------------------------------------------------------
// Kernel A: xp[r][h] = b_ih[h] + b_hh[h] + dot(w_ih[h][:], x[r][:])
// Mapping: lane i = output column h=i. W_ih row i lives in 64 VGPRs (loaded
// once per block). x rows are staged into double-buffered LDS tiles with
// coalesced float4 loads, then broadcast-read (uniform address => free).
// FMA order per output (k ascending, single accumulator) is identical to the
// previous passing kernel => bit-identical xp.
// One wave per block => no s_barrier anywhere; lgkmcnt fences only.
// ---------------------------------------------------------------------------
__global__ __launch_bounds__(64) void xproj(const float* __restrict__ x,
                                            const float* __restrict__ w_ih,
                                            const float* __restrict__ b_ih,
                                            const float* __restrict__ b_hh,
                                            float* __restrict__ dst) {
  __shared__ __align__(16) float xs[2][TR * NH];  // 2 x 4 KB
  const int i = threadIdx.x;
  const size_t rbase = (size_t)blockIdx.x * RPB;

  float4 w[16];
  const float4* wr = (const float4*)(w_ih + (size_t)i * NH);
#pragma unroll
  for (int k = 0; k < 16; ++k) w[k] = wr[k];
  const float bias = b_ih[i] + b_hh[i];

  // preload tile 0 into registers (coalesced: lane-consecutive float4)
  float4 st[4];
  {
    const float4* s0 = (const float4*)(x + rbase * NH);
#pragma unroll
    for (int j = 0; j < 4; ++j) st[j] = s0[j * 64 + i];
  }

  int buf = 0;
#pragma unroll 1
  for (int t = 0; t < RPB / TR; ++t) {
    // stage current tile to LDS (vmcnt auto-wait via register dependency)
    float4* d4 = (float4*)xs[buf];
#pragma unroll
    for (int j = 0; j < 4; ++j) d4[j * 64 + i] = st[j];

    // issue prefetch of next tile (last iter: reload same tile, harmless)
    const int tn = (t + 1 < RPB / TR) ? t + 1 : t;
    const float4* sn = (const float4*)(x + (rbase + (size_t)tn * TR) * NH);
#pragma unroll
    for (int j = 0; j < 4; ++j) st[j] = sn[j * 64 + i];

    // LDS writes visible to the wave; does NOT drain vmcnt (prefetch flies on)
    asm volatile("s_waitcnt lgkmcnt(0)" ::: "memory");

    const float4* xrow = (const float4*)xs[buf];
    const size_t rout = rbase + (size_t)t * TR;
#pragma unroll 4
    for (int rr = 0; rr < TR; ++rr) {
      float a = bias;
#pragma unroll
      for (int j = 0; j < 16; ++j) {
        float4 xk = xrow[rr * 16 + j];   // broadcast read
        a = fmaf(w[j].x, xk.x, a);
        a = fmaf(w[j].y, xk.y, a);
        a = fmaf(w[j].z, xk.z, a);
        a = fmaf(w[j].w, xk.w, a);
      }
      dst[(rout + rr) * NH + i] = a;     // coalesced 256B store
    }
    buf ^= 1;
  }
}

// ---------------------------------------------------------------------------
// Kernel B: sequential scan. One block = ONE WAVE per batch row.
// Key change vs previous version: NO __syncthreads(). A single wave only
// needs s_waitcnt lgkmcnt(0) for LDS write->read visibility; s_barrier forced
// a vmcnt(0) drain of the in-flight prefetch load (~900cy) and the h-store
// (~400cy) onto the critical path EVERY step (1730cy/step measured vs ~300cy
// of real chain). Prefetch deepened to 4 steps (4 x ~330cy > 900cy HBM lat).
// FMA order / tanh identical to previous passing kernel => bit-identical h.
// ---------------------------------------------------------------------------
#define RBODY(XQ, SOFF)                                              \
  {                                                                  \
    float a0 = XQ, a1 = 0.f, a2 = 0.f, a3 = 0.f;                     \
    size_t sp = (size_t)(s + SOFF + 4);                              \
    if (sp > (size_t)(SEQL - 1)) sp = (size_t)(SEQL - 1);            \
    XQ = px[sp * step]; /* prefetch 4 steps ahead, stays in flight */ \
    _Pragma("unroll")                                                \
    for (int j = 0; j < 16; ++j) {                                   \
      float4 hv = h4[j]; /* uniform-address LDS broadcast */         \
      a0 = fmaf(w[j].x, hv.x, a0);                                   \
      a1 = fmaf(w[j].y, hv.y, a1);                                   \
      a2 = fmaf(w[j].z, hv.z, a2);                                   \
      a3 = fmaf(w[j].w, hv.w, a3);                                   \
    }                                                                \
    float z = (a0 + a1) + (a2 + a3);                                 \
    z = fminf(15.f, fmaxf(-15.f, z));                                \
    float e2 = __builtin_amdgcn_exp2f(z * 2.885390081777927f);       \
    float hn = (e2 - 1.f) * __builtin_amdgcn_rcpf(e2 + 1.f);         \
    hs[i] = hn;                                                      \
    po[(size_t)(s + SOFF) * step] = hn; /* fire-and-forget store */  \
    asm volatile("s_waitcnt lgkmcnt(0)" ::: "memory");               \
  }

__device__ __forceinline__ void rec_run(const float* w_hh, const float* xp,
                                        float* out, int b, int i) {
  __shared__ __align__(16) float hs[NH];

  float4 w[16];
  const float4* wr = (const float4*)(w_hh + (size_t)i * NH);
#pragma unroll
  for (int k = 0; k < 16; ++k) w[k] = wr[k];

  hs[i] = 0.f;
  asm volatile("s_waitcnt lgkmcnt(0)" ::: "memory");

  const size_t step = (size_t)NB * NH;
  const float* px = xp + (size_t)b * NH + i;
  float* po = out + (size_t)b * NH + i;
  float xp0 = px[0];
  float xp1 = px[step];
  float xp2 = px[2 * step];
  float xp3 = px[3 * step];
  const float4* h4 = (const float4*)hs;

#pragma unroll 1
  for (int s = 0; s < SEQL; s += 4) {
    RBODY(xp0, 0)
    RBODY(xp1, 1)
    RBODY(xp2, 2)
    RBODY(xp3, 3)
  }
}

// Split variant: xp in workspace, out separate => provably non-aliasing, the
// compiler never has to order the prefetch loads against the h-stores.
__global__ __launch_bounds__(64) void rnn_rec_split(const float* __restrict__ w_hh,
                                                    const float* __restrict__ xp,
                                                    float* __restrict__ out) {
  rec_run(w_hh, xp, out, blockIdx.x, threadIdx.x);
}

// Fallback: in-place (xp slots overwritten by h), as in the previous version.
__global__ __launch_bounds__(64) void rnn_rec_inpl(const float* __restrict__ w_hh,
                                                   float* __restrict__ out) {
  rec_run(w_hh, out, out, blockIdx.x, threadIdx.x);
}

extern "C" void kernel_launch(void* const* d_in, const int* in_sizes, int n_in,
                              void* d_out, int out_size, void* d_ws, size_t ws_size,
                              hipStream_t stream) {
  const float* x    = (const float*)d_in[0];
  const float* w_ih = (const float*)d_in[1];
  const float* w_hh = (const float*)d_in[2];
  const float* b_ih = (const float*)d_in[3];
  const float* b_hh = (const float*)d_in[4];
  float* out = (float*)d_out;

  const size_t need = (size_t)SEQL * NB * NH * sizeof(float);
  if (d_ws && ws_size >= need) {
    float* xpbuf = (float*)d_ws;
    xproj<<<dim3(4096), dim3(64), 0, stream>>>(x, w_ih, b_ih, b_hh, xpbuf);
    rnn_rec_split<<<dim3(NB), dim3(64), 0, stream>>>(w_hh, xpbuf, out);
  } else {
    xproj<<<dim3(4096), dim3(64), 0, stream>>>(x, w_ih, b_ih, b_hh, out);
    rnn_rec_inpl<<<dim3(NB), dim3(64), 0, stream>>>(w_hh, out);
  }
}

// Round 2
// 1643.511 us; speedup vs baseline: 2.1480x; 1.2739x over previous
//
#include <hip/hip_runtime.h>

#define SEQL 4096
#define NB   256
#define NH   64

// Broadcast lane `lane`'s value of v to all lanes, landing in an SGPR.
// v_fma_f32 can consume the SGPR directly (1 SGPR operand allowed per VALU op),
// so this replaces the LDS write->read h-broadcast with zero LDS traffic.
__device__ __forceinline__ float rl(float v, int lane) {
  return __builtin_bit_cast(float,
      __builtin_amdgcn_readlane(__builtin_bit_cast(int, v), lane));
}

// ---------------------------------------------------------------------------
// Kernel A: xp[r][h] = b_ih[h] + b_hh[h] + dot(w_ih[h][:], x[r][:])
// One wave per block; lane i owns output column i with W-row i in 64 VGPRs.
// x broadcast via v_readlane from a coalesced per-lane float4 (4 rows/group),
// NOT via LDS (uniform-address ds_read_b128 issue cost made r1's version
// LDS-pipe-bound at ~600us). Per-output FMA order: single accumulator, k
// ascending 0..63 => bit-identical to rounds 0/1.
// ---------------------------------------------------------------------------
__global__ __launch_bounds__(64) void xproj(const float* __restrict__ x,
                                            const float* __restrict__ w_ih,
                                            const float* __restrict__ b_ih,
                                            const float* __restrict__ b_hh,
                                            float* __restrict__ dst) {
  const int i = threadIdx.x;
  const size_t rbase = (size_t)blockIdx.x * 256;  // 256 rows per wave

  float4 w[16];
  const float4* wr = (const float4*)(w_ih + (size_t)i * NH);
#pragma unroll
  for (int k = 0; k < 16; ++k) w[k] = wr[k];
  const float bias = b_ih[i] + b_hh[i];

  // group g = rows 4g..4g+3. Lane i holds float4 of row (i>>4), elems 4*(i&15)..+3.
  const float4* xg = (const float4*)(x + rbase * NH) + i;
  float* og = dst + rbase * NH + i;

  float4 v = *xg;

#define XROWS()                                               \
  {                                                           \
    _Pragma("unroll")                                         \
    for (int r = 0; r < 4; ++r) {                             \
      float a = bias;                                         \
      _Pragma("unroll")                                       \
      for (int m = 0; m < 16; ++m) {                          \
        float4 wv = w[m];                                     \
        a = fmaf(wv.x, rl(v.x, 16 * r + m), a);               \
        a = fmaf(wv.y, rl(v.y, 16 * r + m), a);               \
        a = fmaf(wv.z, rl(v.z, 16 * r + m), a);               \
        a = fmaf(wv.w, rl(v.w, 16 * r + m), a);               \
      }                                                       \
      og[r * NH] = a;                                         \
    }                                                         \
    og += 4 * NH;                                             \
  }

#pragma unroll 1
  for (int g = 0; g < 63; ++g) {
    float4 vn = xg[64];   // prefetch next group (in bounds for g<63)
    xg += 64;
    XROWS();
    v = vn;
  }
  XROWS();                // last group, no prefetch
#undef XROWS
}

// ---------------------------------------------------------------------------
// Kernel B: sequential scan, one wave per batch row. ZERO LDS: h[j] broadcast
// via v_readlane (lane j holds h[j]); FMA consumes the SGPR directly.
// Removes the ds_write -> lgkmcnt -> 16x ds_read_b128 round trip (~550cy of
// the measured 871cy/step). Pointer-bumped addressing (no per-step 64-bit
// mul), tail-peeled prefetch (no clamp). FMA order / combine / tanh are
// bit-identical to rounds 0/1 => absmax must stay 0.00390625.
// ---------------------------------------------------------------------------
__device__ __forceinline__ void rec_run(const float* __restrict__ w_hh,
                                        const float* __restrict__ xp,
                                        float* __restrict__ out, int b, int i) {
  float4 w[16];
  const float4* wr = (const float4*)(w_hh + (size_t)i * NH);
#pragma unroll
  for (int k = 0; k < 16; ++k) w[k] = wr[k];

  const size_t step = (size_t)NB * NH;           // 16384 floats per timestep
  const float* px = xp + (size_t)b * NH + i;     // prefetch cursor
  float* po = out + (size_t)b * NH + i;          // store cursor

  float xq0 = px[0];
  float xq1 = px[step];
  float xq2 = px[2 * step];
  float xq3 = px[3 * step];
  px += 4 * step;

  float hn = 0.f;                                // lane's own h[i]

#define RSTEP(XQ, PF)                                            \
  {                                                              \
    float a0 = XQ, a1 = 0.f, a2 = 0.f, a3 = 0.f;                 \
    if (PF) { XQ = px[0]; px += step; }  /* 4-deep prefetch */   \
    _Pragma("unroll")                                            \
    for (int m = 0; m < 16; ++m) {                               \
      float4 wv = w[m];                                          \
      a0 = fmaf(wv.x, rl(hn, 4 * m + 0), a0);                    \
      a1 = fmaf(wv.y, rl(hn, 4 * m + 1), a1);                    \
      a2 = fmaf(wv.z, rl(hn, 4 * m + 2), a2);                    \
      a3 = fmaf(wv.w, rl(hn, 4 * m + 3), a3);                    \
    }                                                            \
    float z = (a0 + a1) + (a2 + a3);                             \
    z = fminf(15.f, fmaxf(-15.f, z));                            \
    float e2 = __builtin_amdgcn_exp2f(z * 2.885390081777927f);   \
    hn = (e2 - 1.f) * __builtin_amdgcn_rcpf(e2 + 1.f);           \
    po[0] = hn;                                                  \
    po += step;                                                  \
  }

#pragma unroll 1
  for (int s = 0; s < SEQL - 4; s += 4) {
    RSTEP(xq0, 1) RSTEP(xq1, 1) RSTEP(xq2, 1) RSTEP(xq3, 1)
  }
  RSTEP(xq0, 0) RSTEP(xq1, 0) RSTEP(xq2, 0) RSTEP(xq3, 0)
#undef RSTEP
}

// Split variant: xp in workspace => px/po provably non-aliasing.
__global__ __launch_bounds__(64) void rnn_rec_split(const float* __restrict__ w_hh,
                                                    const float* __restrict__ xp,
                                                    float* __restrict__ out) {
  rec_run(w_hh, xp, out, blockIdx.x, threadIdx.x);
}

// Fallback: in-place (reads xp[s+4] before overwriting slot s; program order
// keeps it correct even with conservative aliasing).
__global__ __launch_bounds__(64) void rnn_rec_inpl(const float* __restrict__ w_hh,
                                                   float* __restrict__ out) {
  rec_run(w_hh, out, out, blockIdx.x, threadIdx.x);
}

extern "C" void kernel_launch(void* const* d_in, const int* in_sizes, int n_in,
                              void* d_out, int out_size, void* d_ws, size_t ws_size,
                              hipStream_t stream) {
  const float* x    = (const float*)d_in[0];
  const float* w_ih = (const float*)d_in[1];
  const float* w_hh = (const float*)d_in[2];
  const float* b_ih = (const float*)d_in[3];
  const float* b_hh = (const float*)d_in[4];
  float* out = (float*)d_out;

  const size_t need = (size_t)SEQL * NB * NH * sizeof(float);
  if (d_ws && ws_size >= need) {
    float* xpbuf = (float*)d_ws;
    xproj<<<dim3(4096), dim3(64), 0, stream>>>(x, w_ih, b_ih, b_hh, xpbuf);
    rnn_rec_split<<<dim3(NB), dim3(64), 0, stream>>>(w_hh, xpbuf, out);
  } else {
    xproj<<<dim3(4096), dim3(64), 0, stream>>>(x, w_ih, b_ih, b_hh, out);
    rnn_rec_inpl<<<dim3(NB), dim3(64), 0, stream>>>(w_hh, out);
  }
}